// Round 3
// baseline (57.445 us; speedup 1.0000x reference)
//
#include <hip/hip_runtime.h>

// Segmented histogram, node-chunked:
//   out[g, c] = sum of w[i] for i in [ptr[g], ptr[g+1]) with x[i] == c < out_dim.
//
// Round-2 lesson: one-block-per-graph is latency-bound (burst-then-wait, ~1 TB/s
// effective). Here blocks own equal 2048-node chunks: stage chunk to LDS in one
// deep coalesced burst, then bin per-graph from LDS. Graphs interior to a chunk
// are direct-stored; graphs straddling chunk boundaries are pre-zeroed by the
// setup kernel and atomically accumulated.

#define CHUNK   2048
#define BLOCK_B 256

// One block per chunk boundary b in [0, n_chunks]: finds the graph containing
// node min(b*CHUNK, N-1) -> gstart[b], and zeroes that (shared) output row.
extern "C" __global__ __launch_bounds__(64)
void setup_kernel(const int* __restrict__ ptr, int* __restrict__ gstart,
                  float* __restrict__ out, int n_nodes, int num_graphs,
                  int out_dim) {
    const int b = blockIdx.x;
    long n0 = (long)b * CHUNK;
    if (n0 > (long)n_nodes - 1) n0 = (long)n_nodes - 1;

    // upper_bound(ptr[0..num_graphs], n0) - 1  (all 64 lanes redundantly, uniform)
    int lo = 0, hi = num_graphs + 1;
    while (lo < hi) {
        const int mid = (lo + hi) >> 1;
        if ((long)ptr[mid] <= n0) lo = mid + 1; else hi = mid;
    }
    const int g = lo - 1;  // in [0, num_graphs-1]

    if (threadIdx.x == 0) gstart[b] = g;

    float* row = out + (size_t)g * (size_t)out_dim;
    for (int c = (int)threadIdx.x; c < out_dim; c += 64) row[c] = 0.0f;
}

extern "C" __global__ __launch_bounds__(BLOCK_B)
void hist_kernel(const int* __restrict__ x, const int* __restrict__ ptr,
                 const float* __restrict__ w, const int* __restrict__ gstart,
                 float* __restrict__ out, int n_nodes, int out_dim) {
    extern __shared__ char smem[];
    int*   xbuf = (int*)smem;
    float* wbuf = (float*)(smem + CHUNK * sizeof(int));
    float* hist = (float*)(smem + CHUNK * sizeof(int) + CHUNK * sizeof(float));

    const int b   = blockIdx.x;
    const int t   = (int)threadIdx.x;
    const int n0  = b * CHUNK;
    const int n1  = min(n0 + CHUNK, n_nodes);
    const int cnt = n1 - n0;

    // ---- phase 1: stage chunk into LDS, one deep coalesced burst ----
    for (int base = 0; base < cnt; base += 4 * BLOCK_B) {
        const int idx = base + t * 4;
        if (idx + 4 <= cnt) {
            *reinterpret_cast<int4*>(&xbuf[idx])   = *reinterpret_cast<const int4*>(&x[n0 + idx]);
            *reinterpret_cast<float4*>(&wbuf[idx]) = *reinterpret_cast<const float4*>(&w[n0 + idx]);
        } else if (idx < cnt) {
            for (int k = idx; k < cnt; ++k) { xbuf[k] = x[n0 + k]; wbuf[k] = w[n0 + k]; }
        }
    }

    const int g0 = gstart[b];
    const int g1 = gstart[b + 1];
    __syncthreads();

    // ---- phase 2: per-graph binning from LDS ----
    int pjs = ptr[g0];
    for (int j = g0; j <= g1; ++j) {
        const int pje = ptr[j + 1];
        const int s = max(pjs, n0) - n0;
        const int e = min(pje, n1) - n0;

        for (int c = t; c < out_dim; c += BLOCK_B) hist[c] = 0.0f;
        __syncthreads();

        for (int i = s + t; i < e; i += BLOCK_B) {
            const unsigned lbl = (unsigned)xbuf[i];
            if (lbl < (unsigned)out_dim) atomicAdd(&hist[lbl], wbuf[i]);
        }
        __syncthreads();

        float* row = out + (size_t)j * (size_t)out_dim;
        if (j == g0 || j == g1) {
            // boundary graph: shared with neighbor chunk(s); row pre-zeroed by setup
            for (int c = t; c < out_dim; c += BLOCK_B) {
                const float v = hist[c];
                if (v != 0.0f) atomicAdd(&row[c], v);
            }
        } else {
            // interior graph: exclusively owned -> direct store (also covers empty graphs)
            for (int c = t; c < out_dim; c += BLOCK_B) row[c] = hist[c];
        }
        pjs = pje;
    }
}

// Fallback (round-1 structure) if d_ws is too small for gstart.
extern "C" __global__ __launch_bounds__(256)
void seg_hist_fallback(const int* __restrict__ x, const int* __restrict__ ptr,
                       const float* __restrict__ w, float* __restrict__ out,
                       int out_dim) {
    extern __shared__ float fhist[];
    const int g = blockIdx.x;
    const int start = ptr[g];
    const int end = ptr[g + 1];
    for (int c = (int)threadIdx.x; c < out_dim; c += 256) fhist[c] = 0.0f;
    __syncthreads();
    for (int i = start + (int)threadIdx.x; i < end; i += 256) {
        const int lbl = x[i];
        if ((unsigned)lbl < (unsigned)out_dim) atomicAdd(&fhist[lbl], w[i]);
    }
    __syncthreads();
    float* o = out + (size_t)g * (size_t)out_dim;
    for (int c = (int)threadIdx.x; c < out_dim; c += 256) o[c] = fhist[c];
}

extern "C" void kernel_launch(void* const* d_in, const int* in_sizes, int n_in,
                              void* d_out, int out_size, void* d_ws, size_t ws_size,
                              hipStream_t stream) {
    const int* x   = (const int*)d_in[0];
    const int* ptr = (const int*)d_in[1];
    const float* w = (const float*)d_in[2];
    float* out     = (float*)d_out;

    const int n_nodes    = in_sizes[0];
    const int num_graphs = in_sizes[1] - 1;
    const int out_dim    = out_size / num_graphs;   // 256
    const int n_chunks   = (n_nodes + CHUNK - 1) / CHUNK;

    if (ws_size < (size_t)(n_chunks + 1) * sizeof(int)) {
        // scratch too small: fall back to one-block-per-graph
        seg_hist_fallback<<<num_graphs, 256, (size_t)out_dim * sizeof(float), stream>>>(
            x, ptr, w, out, out_dim);
        return;
    }

    int* gstart = (int*)d_ws;

    setup_kernel<<<n_chunks + 1, 64, 0, stream>>>(ptr, gstart, out,
                                                  n_nodes, num_graphs, out_dim);

    const size_t lds = (size_t)CHUNK * 8 + (size_t)out_dim * sizeof(float);
    hist_kernel<<<n_chunks, BLOCK_B, lds, stream>>>(x, ptr, w, gstart, out,
                                                    n_nodes, out_dim);
}

// Round 4
// 55.174 us; speedup vs baseline: 1.0412x; 1.0412x over previous
//
#include <hip/hip_runtime.h>

// Segmented histogram: out[g, c] = sum of w[i] for i in [ptr[g], ptr[g+1])
// with x[i] == c < out_dim.
//
// Round-3 lesson: every burst-then-bin structure lands at ~52us because memory
// is only in flight a small fraction of block lifetime (latency-bound at
// ~1 TB/s). This version register-stages each thread's 8 contiguous nodes in
// one up-front 64B burst (no barrier before first use -> loads stay in flight
// under other blocks' binning), and bins from registers into a 1KB LDS hist
// with statically-unrolled predicated atomics + wave-uniform phase skip.

#define CHUNK   2048   // nodes per block
#define NPT     8      // nodes per thread
#define BLOCK_B 256
#define ODIM    256    // compiled for out_dim == 256 (host falls back otherwise)

// One block per chunk boundary b in [0, n_chunks]: gstart[b] = graph containing
// node min(b*CHUNK, N-1); zero that (shared) output row.
extern "C" __global__ __launch_bounds__(64)
void setup_kernel(const int* __restrict__ ptr, int* __restrict__ gstart,
                  float* __restrict__ out, int n_nodes, int num_graphs,
                  int out_dim) {
    const int b = blockIdx.x;
    long n0 = (long)b * CHUNK;
    if (n0 > (long)n_nodes - 1) n0 = (long)n_nodes - 1;

    int lo = 0, hi = num_graphs + 1;
    while (lo < hi) {
        const int mid = (lo + hi) >> 1;
        if ((long)ptr[mid] <= n0) lo = mid + 1; else hi = mid;
    }
    const int g = lo - 1;

    if (threadIdx.x == 0) gstart[b] = g;

    float* row = out + (size_t)g * (size_t)out_dim;
    for (int c = (int)threadIdx.x; c < out_dim; c += 64) row[c] = 0.0f;
}

extern "C" __global__ __launch_bounds__(BLOCK_B, 6)
void hist_kernel(const int* __restrict__ x, const int* __restrict__ ptr,
                 const float* __restrict__ w, const int* __restrict__ gstart,
                 float* __restrict__ out, int n_nodes, int num_graphs) {
    __shared__ float hist[ODIM];

    const int b  = blockIdx.x;
    const int t  = (int)threadIdx.x;
    const int n0 = b * CHUNK;
    const int n1 = min(n0 + CHUNK, n_nodes);

    // ---- register-stage this thread's 8 contiguous nodes (issued up front) ----
    const int base = n0 + t * NPT;
    int4 la, lb; float4 wa, wb;
    if (base + NPT <= n1) {
        la = *reinterpret_cast<const int4*>(x + base);
        lb = *reinterpret_cast<const int4*>(x + base + 4);
        wa = *reinterpret_cast<const float4*>(w + base);
        wb = *reinterpret_cast<const float4*>(w + base + 4);
    } else {
        int l[NPT]; float ww[NPT];
#pragma unroll
        for (int k = 0; k < NPT; ++k) {
            if (base + k < n1) { l[k] = x[base + k]; ww[k] = w[base + k]; }
            else               { l[k] = 0x7fffffff;  ww[k] = 0.0f; }
        }
        la = make_int4(l[0], l[1], l[2], l[3]);
        lb = make_int4(l[4], l[5], l[6], l[7]);
        wa = make_float4(ww[0], ww[1], ww[2], ww[3]);
        wb = make_float4(ww[4], ww[5], ww[6], ww[7]);
    }

    const int g0 = gstart[b];
    const int g1 = gstart[b + 1];
    // cover leading/trailing empty graphs (not contained in any gstart window)
    int jbeg = g0, jend = g1;
    if (b == 0) jbeg = 0;
    if (b == (int)gridDim.x - 1) jend = num_graphs - 1;

    hist[t] = 0.0f;          // ODIM == BLOCK_B
    __syncthreads();

    const int i0    = t * NPT;          // chunk-local first node of this thread
    const int wbase = (t & ~63) * NPT;  // chunk-local first node of this wave

    int pjs = ptr[jbeg];
    for (int j = jbeg; j <= jend; ++j) {
        const int pje = ptr[j + 1];
        const int s = max(pjs, n0) - n0;
        const int e = min(pje, n1) - n0;

        // wave-uniform skip: does this wave's 512-node span intersect [s,e)?
        if (s < e && e > wbase && s < wbase + 64 * NPT) {
#define ADDK(LBL, WV, K)                                               \
            { const int ii = i0 + (K);                                 \
              if (ii >= s && ii < e && (unsigned)(LBL) < (unsigned)ODIM) \
                  atomicAdd(&hist[LBL], (WV)); }
            ADDK(la.x, wa.x, 0) ADDK(la.y, wa.y, 1)
            ADDK(la.z, wa.z, 2) ADDK(la.w, wa.w, 3)
            ADDK(lb.x, wb.x, 4) ADDK(lb.y, wb.y, 5)
            ADDK(lb.z, wb.z, 6) ADDK(lb.w, wb.w, 7)
#undef ADDK
        }
        __syncthreads();

        // flush + re-zero (thread t owns bin t)
        float* row = out + (size_t)j * ODIM;
        const float v = hist[t];
        if (j == g0 || j == g1) {
            if (v != 0.0f) atomicAdd(&row[t], v);   // boundary row, pre-zeroed
        } else {
            row[t] = v;                              // exclusively owned
        }
        hist[t] = 0.0f;
        __syncthreads();

        pjs = pje;
    }
}

// Fallback (round-1 structure) for out_dim != 256 or tiny workspace.
extern "C" __global__ __launch_bounds__(256)
void seg_hist_fallback(const int* __restrict__ x, const int* __restrict__ ptr,
                       const float* __restrict__ w, float* __restrict__ out,
                       int out_dim) {
    extern __shared__ float fhist[];
    const int g = blockIdx.x;
    const int start = ptr[g];
    const int end = ptr[g + 1];
    for (int c = (int)threadIdx.x; c < out_dim; c += 256) fhist[c] = 0.0f;
    __syncthreads();
    for (int i = start + (int)threadIdx.x; i < end; i += 256) {
        const int lbl = x[i];
        if ((unsigned)lbl < (unsigned)out_dim) atomicAdd(&fhist[lbl], w[i]);
    }
    __syncthreads();
    float* o = out + (size_t)g * (size_t)out_dim;
    for (int c = (int)threadIdx.x; c < out_dim; c += 256) o[c] = fhist[c];
}

extern "C" void kernel_launch(void* const* d_in, const int* in_sizes, int n_in,
                              void* d_out, int out_size, void* d_ws, size_t ws_size,
                              hipStream_t stream) {
    const int* x   = (const int*)d_in[0];
    const int* ptr = (const int*)d_in[1];
    const float* w = (const float*)d_in[2];
    float* out     = (float*)d_out;

    const int n_nodes    = in_sizes[0];
    const int num_graphs = in_sizes[1] - 1;
    const int out_dim    = out_size / num_graphs;
    const int n_chunks   = (n_nodes + CHUNK - 1) / CHUNK;

    if (out_dim != ODIM || ws_size < (size_t)(n_chunks + 1) * sizeof(int)) {
        seg_hist_fallback<<<num_graphs, 256, (size_t)out_dim * sizeof(float), stream>>>(
            x, ptr, w, out, out_dim);
        return;
    }

    int* gstart = (int*)d_ws;

    setup_kernel<<<n_chunks + 1, 64, 0, stream>>>(ptr, gstart, out,
                                                  n_nodes, num_graphs, out_dim);

    hist_kernel<<<n_chunks, BLOCK_B, 0, stream>>>(x, ptr, w, gstart, out,
                                                  n_nodes, num_graphs);
}